// Round 12
// baseline (421.639 us; speedup 1.0000x reference)
//
#include <hip/hip_runtime.h>
#include <hip/hip_bf16.h>

#define NN 50000
#define NE 800000
#define NB 196     // bins: node>>8 -> 0..195
#define BCAPD 4608 // per-dst-bin record capacity (mean 4082, +8 sigma)
#define BCAPS 4608
#define EPT 4      // edges per thread in k_bin (1024/block -> 782 blocks)
#define BIN_BLOCKS ((NE + 256*EPT - 1) / (256*EPT))

typedef __attribute__((ext_vector_type(4))) float f4;
typedef __attribute__((ext_vector_type(4))) float f32x4;
typedef __attribute__((ext_vector_type(8))) short bf16x8;
typedef __attribute__((ext_vector_type(4))) unsigned int u32x4;
typedef __attribute__((ext_vector_type(2))) unsigned int u32x2;

// ---- ws layout (in floats), no aliasing ----
#define OFF_BIND 0                        // int2 [NB*BCAPD] (src|dlo<<16, f32 w)
#define OFF_BINS (2*NB*BCAPD)             // u32  [NB*BCAPS] (slo<<16 | bf16 w)
#define OFF_DINV (OFF_BINS + NB*BCAPS)    // [NN] 1/sqrt(deg)
#define OFF_GC   (OFF_DINV + NN)          // [2*NB] bin cursors (D then S)
#define OFF_BIAS (OFF_GC + 2*NB)          // [196] bz|bh|linW|linb
#define OFF_WT   (OFF_BIAS + 196)         // u16[2][64][128] bf16 W^T
#define OFF_XB   (OFF_WT + 8192)          // u32[NN*32] bf16-pair x
#define OFF_TX1  (OFF_XB + NN*32)         // u32[NN*32] bf16-pair tx1

__device__ __forceinline__ unsigned int bpack(float a, float b) {
    return ((__float_as_uint(a) + 0x8000u) >> 16)
         | ((__float_as_uint(b) + 0x8000u) & 0xffff0000u);
}
__device__ __forceinline__ float b2f(unsigned short u) {
    return __uint_as_float((unsigned int)u << 16);
}

// K1: pack x->bf16, W^T bf16, fold biases, zero bin cursors (runs before k_bin).
__global__ __launch_bounds__(256) void k_prep(const float* __restrict__ x,
                       const float* __restrict__ Wxz, const float* __restrict__ bxz,
                       const float* __restrict__ bhz,
                       const float* __restrict__ Wxh, const float* __restrict__ bxh,
                       const float* __restrict__ bhh,
                       const float* __restrict__ linW, const float* __restrict__ linb,
                       float* __restrict__ bias, unsigned short* __restrict__ wt,
                       unsigned int* __restrict__ xb, int* __restrict__ gc) {
    int idx = blockIdx.x * 256 + threadIdx.x;
    if (idx < NN * 16) {   // 4 f32 each
        f4 v = *(const f4*)&x[(size_t)idx * 4];
        u32x2 p = { bpack(v[0], v[1]), bpack(v[2], v[3]) };
        *(u32x2*)&xb[(size_t)idx * 2] = p;
    }
    if (idx < 2 * 64 * 128) {
        int g = idx >> 13;
        int c = (idx >> 7) & 63;
        int k = idx & 127;
        const float* W = g ? Wxh : Wxz;
        float v = (k < 64) ? W[k * 64 + c] : W[4096 + (k - 64) * 64 + c];
        wt[idx] = (unsigned short)((__float_as_uint(v) + 0x8000u) >> 16);
    }
    if (idx < 64) {
        bias[idx]       = bxz[idx] + bhz[idx];
        bias[64 + idx]  = bxh[idx] + bhh[idx];
        bias[128 + idx] = linW[idx];
    }
    if (idx == 64) bias[192] = linb[0];
    if (idx < 2 * NB) gc[idx] = 0;
}

// K2: LDS-aggregated binning by dst (8B records, f32 w) and src (4B bf16 w).
__global__ __launch_bounds__(256) void k_bin(const int* __restrict__ ei,
                                             const float* __restrict__ ew,
                                             int2* __restrict__ binD,
                                             unsigned int* __restrict__ binS,
                                             int* __restrict__ gcD, int* __restrict__ gcS) {
    __shared__ int hD[NB], hS[NB], bD[NB], bS[NB];
    int t = threadIdx.x;
    for (int b = t; b < NB; b += 256) { hD[b] = 0; hS[b] = 0; }
    __syncthreads();
    int e0 = blockIdx.x * (256 * EPT);
    unsigned int sa[EPT];  // src | dlo<<16 | binD<<24
    float wv[EPT];
    int sd[EPT], ss[EPT];
#pragma unroll
    for (int i = 0; i < EPT; i++) {
        int e = e0 + i * 256 + t;
        sd[i] = -1; ss[i] = -1; sa[i] = 0; wv[i] = 0.f;
        if (e < NE) {
            int s = ei[e];
            int d = ei[NE + e];
            wv[i] = ew[e];
            int bind = d >> 8;
            sa[i] = (unsigned int)s | ((unsigned int)(d & 255) << 16)
                  | ((unsigned int)bind << 24);
            sd[i] = atomicAdd(&hD[bind], 1);
            ss[i] = atomicAdd(&hS[s >> 8], 1);
        }
    }
    __syncthreads();
    for (int b = t; b < NB; b += 256) {
        bD[b] = atomicAdd(&gcD[b], hD[b]);
        bS[b] = atomicAdd(&gcS[b], hS[b]);
    }
    __syncthreads();
#pragma unroll
    for (int i = 0; i < EPT; i++) {
        if (sd[i] < 0) continue;
        unsigned int a = sa[i];
        int bind = a >> 24;
        int src  = a & 0xffff;
        int pD = bD[bind] + sd[i];
        if (pD < BCAPD)
            binD[bind * BCAPD + pD] = make_int2((int)(a & 0xffffff),
                                                __float_as_int(wv[i]));
        int bins = src >> 8;
        int pS = bS[bins] + ss[i];
        if (pS < BCAPS)
            binS[bins * BCAPS + pS] = ((unsigned int)(src & 255) << 16)
                                    | ((__float_as_uint(wv[i]) + 0x8000u) >> 16);
    }
}

// K3: src-binned weights -> deg via LDS f32 adds; writes dinv.
__global__ __launch_bounds__(1024) void k_deg(const unsigned int* __restrict__ binS,
                                              const int* __restrict__ gcS,
                                              float* __restrict__ dinv) {
    __shared__ float acc[256];
    int bin = blockIdx.x;
    int t = threadIdx.x;
    if (t < 256) acc[t] = 0.f;
    __syncthreads();
    int m = gcS[bin]; if (m > BCAPS) m = BCAPS;
    const unsigned int* bp = binS + (size_t)bin * BCAPS;
    for (int j = t; j < m; j += 1024) {
        unsigned int r = bp[j];
        atomicAdd(&acc[r >> 16], __uint_as_float((r & 0xffffu) << 16));
    }
    __syncthreads();
    if (t < 256) {
        int idx = bin * 256 + t;
        if (idx < NN) {
            float d = acc[t];
            dinv[idx] = (d > 0.f) ? (1.f / sqrtf(d)) : 0.f;
        }
    }
}

// K4 (fused bucket+gather): block per dst-bin; 64KB LDS f32 tile [256 nodes][64 ch].
// Wave-serial records: uniform 8B record + uniform dinv[src] + coalesced 128B bf16
// x-row; one conflict-free ds_add_f32 per lane. Epilogue scales rows by -dinv[dst]
// and stores bf16 tx1. Eliminates erec/cnt and the separate gather pass.
__global__ __launch_bounds__(1024) void k_gb(const int2* __restrict__ binD,
                                             const int* __restrict__ gcD,
                                             const float* __restrict__ dinv,
                                             const unsigned short* __restrict__ xb16,
                                             unsigned int* __restrict__ tx1) {
    __shared__ float acc[256 * 64];  // 64 KB
    int bin = blockIdx.x;
    int t = threadIdx.x;
    for (int i = t; i < 256 * 64; i += 1024) acc[i] = 0.f;
    __syncthreads();

    int m = gcD[bin]; if (m > BCAPD) m = BCAPD;
    const int2* bp = binD + (size_t)bin * BCAPD;
    int wid = t >> 6, lane = t & 63;
    int chunk = ((((m + 15) >> 4) + 3) & ~3);       // per-wave range, 4-aligned
    int r0 = wid * chunk;
    int r1 = r0 + chunk; if (r1 > m) r1 = m;
    int i = r0;
    for (; i + 3 < r1; i += 4) {
        int4 ra = *(const int4*)&bp[i];      // recs i, i+1 (uniform, 16B)
        int4 rb = *(const int4*)&bp[i + 2];  // recs i+2, i+3
        int s0 = ra.x & 0xffff, s1 = ra.z & 0xffff;
        int s2 = rb.x & 0xffff, s3 = rb.z & 0xffff;
        float n0 = __int_as_float(ra.y) * dinv[s0];
        float n1 = __int_as_float(ra.w) * dinv[s1];
        float n2 = __int_as_float(rb.y) * dinv[s2];
        float n3 = __int_as_float(rb.w) * dinv[s3];
        float x0 = b2f(xb16[(size_t)s0 * 64 + lane]);
        float x1 = b2f(xb16[(size_t)s1 * 64 + lane]);
        float x2 = b2f(xb16[(size_t)s2 * 64 + lane]);
        float x3 = b2f(xb16[(size_t)s3 * 64 + lane]);
        atomicAdd(&acc[((ra.x >> 16) & 255) * 64 + lane], n0 * x0);
        atomicAdd(&acc[((ra.z >> 16) & 255) * 64 + lane], n1 * x1);
        atomicAdd(&acc[((rb.x >> 16) & 255) * 64 + lane], n2 * x2);
        atomicAdd(&acc[((rb.z >> 16) & 255) * 64 + lane], n3 * x3);
    }
    for (; i < r1; i++) {
        int2 e = bp[i];
        int s = e.x & 0xffff;
        float n = __int_as_float(e.y) * dinv[s];
        float xv = b2f(xb16[(size_t)s * 64 + lane]);
        atomicAdd(&acc[((e.x >> 16) & 255) * 64 + lane], n * xv);
    }
    __syncthreads();

    int d = t >> 2, p = t & 3;                   // row, quarter
    int node = bin * 256 + d;
    if (node < NN) {
        float sc = -dinv[node];
        const float* a = &acc[d * 64 + p * 16];
        u32x4 o0 = { bpack(sc * a[0],  sc * a[1]),  bpack(sc * a[2],  sc * a[3]),
                     bpack(sc * a[4],  sc * a[5]),  bpack(sc * a[6],  sc * a[7]) };
        u32x4 o1 = { bpack(sc * a[8],  sc * a[9]),  bpack(sc * a[10], sc * a[11]),
                     bpack(sc * a[12], sc * a[13]), bpack(sc * a[14], sc * a[15]) };
        *(u32x4*)&tx1[(size_t)node * 32 + p * 8]     = o0;
        *(u32x4*)&tx1[(size_t)node * 32 + p * 8 + 4] = o1;
    }
}

// K5: MFMA node kernel (unchanged, validated rounds 9-11): wave = 16 nodes,
// A-frags straight from global bf16 x||tx1; C/D col=lane&15, row=(lane>>4)*4+reg.
__global__ __launch_bounds__(256) void k_node(const unsigned int* __restrict__ xb,
                                              const unsigned int* __restrict__ tx1,
                                              const unsigned short* __restrict__ WT,
                                              const float* __restrict__ bias,
                                              float* __restrict__ out) {
    int lane = threadIdx.x & 63;
    int base = (blockIdx.x * 4 + (threadIdx.x >> 6)) * 16;
    if (base >= NN) return;

    int m  = lane & 15;
    int kg = lane >> 4;
    size_t node = (size_t)(base + m);

    bf16x8 afr[4];
    afr[0] = *(const bf16x8*)&xb[node * 32 + kg * 4];
    afr[1] = *(const bf16x8*)&xb[node * 32 + 16 + kg * 4];
    afr[2] = *(const bf16x8*)&tx1[node * 32 + kg * 4];
    afr[3] = *(const bf16x8*)&tx1[node * 32 + 16 + kg * 4];

    const unsigned short* Wl = WT + m * 128 + kg * 8;
    f32x4 az4[4], ah4[4];
#pragma unroll
    for (int nt = 0; nt < 4; nt++) { az4[nt] = (f32x4){0,0,0,0}; ah4[nt] = (f32x4){0,0,0,0}; }

#pragma unroll
    for (int nt = 0; nt < 4; nt++) {
#pragma unroll
        for (int kt = 0; kt < 4; kt++) {
            bf16x8 bz = *(const bf16x8*)(Wl + nt * 2048 + kt * 32);
            bf16x8 bh = *(const bf16x8*)(Wl + 8192 + nt * 2048 + kt * 32);
            az4[nt] = __builtin_amdgcn_mfma_f32_16x16x32_bf16(afr[kt], bz, az4[nt], 0, 0, 0);
            ah4[nt] = __builtin_amdgcn_mfma_f32_16x16x32_bf16(afr[kt], bh, ah4[nt], 0, 0, 0);
        }
    }

    float vout[4] = {0.f, 0.f, 0.f, 0.f};
#pragma unroll
    for (int nt = 0; nt < 4; nt++) {
        int col = nt * 16 + m;
        float bz = bias[col], bh = bias[64 + col], lw = bias[128 + col];
#pragma unroll
        for (int r = 0; r < 4; r++) {
            float az = az4[nt][r] + bz;
            float ah = ah4[nt][r] + bh;
            float ez = __expf(-az);
            float z  = __builtin_amdgcn_rcpf(1.f + ez);
            float eh = __expf(2.f * ah);
            float th = (eh - 1.f) * __builtin_amdgcn_rcpf(eh + 1.f);
            float h  = (1.f - z) * th;
            h = (h > 0.f) ? h : 0.f;
            vout[r] = fmaf(h, lw, vout[r]);
        }
    }
    float LB = bias[192];
#pragma unroll
    for (int r = 0; r < 4; r++) {
        float v = vout[r];
        v += __shfl_xor(v, 1);
        v += __shfl_xor(v, 2);
        v += __shfl_xor(v, 4);
        v += __shfl_xor(v, 8);
        if (m == 0) out[base + kg * 4 + r] = v + LB;
    }
}

extern "C" void kernel_launch(void* const* d_in, const int* in_sizes, int n_in,
                              void* d_out, int out_size, void* d_ws, size_t ws_size,
                              hipStream_t stream) {
    const float* x   = (const float*)d_in[0];
    const int*   ei  = (const int*)d_in[1];
    const float* ew  = (const float*)d_in[2];
    const float* Wxz = (const float*)d_in[3];
    const float* bxz = (const float*)d_in[4];
    const float* bhz = (const float*)d_in[6];
    const float* Wxh = (const float*)d_in[11];
    const float* bxh = (const float*)d_in[12];
    const float* bhh = (const float*)d_in[14];
    const float* lW  = (const float*)d_in[15];
    const float* lb  = (const float*)d_in[16];
    float* ws  = (float*)d_ws;
    float* out = (float*)d_out;

    k_prep<<<(NN * 16 + 255) / 256, 256, 0, stream>>>(
        x, Wxz, bxz, bhz, Wxh, bxh, bhh, lW, lb,
        ws + OFF_BIAS, (unsigned short*)(ws + OFF_WT),
        (unsigned int*)(ws + OFF_XB), (int*)(ws + OFF_GC));
    k_bin<<<BIN_BLOCKS, 256, 0, stream>>>(ei, ew,
                                          (int2*)(ws + OFF_BIND),
                                          (unsigned int*)(ws + OFF_BINS),
                                          (int*)(ws + OFF_GC), (int*)(ws + OFF_GC) + NB);
    k_deg<<<NB, 1024, 0, stream>>>((const unsigned int*)(ws + OFF_BINS),
                                   (const int*)(ws + OFF_GC) + NB, ws + OFF_DINV);
    k_gb<<<NB, 1024, 0, stream>>>((const int2*)(ws + OFF_BIND),
                                  (const int*)(ws + OFF_GC), ws + OFF_DINV,
                                  (const unsigned short*)(ws + OFF_XB),
                                  (unsigned int*)(ws + OFF_TX1));
    k_node<<<(NN + 63) / 64, 256, 0, stream>>>(
        (const unsigned int*)(ws + OFF_XB), (const unsigned int*)(ws + OFF_TX1),
        (const unsigned short*)(ws + OFF_WT), ws + OFF_BIAS, out);
}

// Round 13
// 102.727 us; speedup vs baseline: 4.1044x; 4.1044x over previous
//
#include <hip/hip_runtime.h>
#include <hip/hip_bf16.h>

#define NN 50000
#define NE 800000
#define NB 196     // bins: node>>8 -> 0..195
#define BCAPD 4608 // per-bin capacity (mean 4082, +8 sigma)
#define BCAPS 4608
#define EPT 4      // edges per thread in k_bin (1024/block -> 782 blocks)
#define BIN_BLOCKS ((NE + 256*EPT - 1) / (256*EPT))

typedef __attribute__((ext_vector_type(4))) float f4;
typedef __attribute__((ext_vector_type(4))) float f32x4;
typedef __attribute__((ext_vector_type(8))) short bf16x8;
typedef __attribute__((ext_vector_type(4))) unsigned int u32x4;
typedef __attribute__((ext_vector_type(2))) unsigned int u32x2;

// ---- ws layout (in floats), no aliasing ----
#define OFF_BIND 0                        // int2 [NB*BCAPD] (src|dlo<<16, f32 w)
#define OFF_BINS (2*NB*BCAPD)             // u32  [NB*BCAPS] (slo<<16 | bf16 w)
#define OFF_DINV (OFF_BINS + NB*BCAPS)    // [NN] 1/sqrt(deg)
#define OFF_CNT  (OFF_DINV + NN)          // [NN] in-degree counts
#define OFF_GC   (OFF_CNT + NN)           // [2*NB] bin cursors (D then S)
#define OFF_BIAS (OFF_GC + 2*NB)          // [196] bz|bh|linW|linb
#define OFF_WT   (OFF_BIAS + 196)         // u16[2][64][128] bf16 W^T
#define OFF_TX1  (OFF_WT + 8192)          // u32[NN*32] bf16-pair tx1
#define OFF_EREC (OFF_TX1 + NN*32)        // u32[NN*cap] records (src<<16 | bf16 w)

__device__ __forceinline__ unsigned int bpack(float a, float b) {
    return ((__float_as_uint(a) + 0x8000u) >> 16)
         | ((__float_as_uint(b) + 0x8000u) & 0xffff0000u);
}

// K1 (tiny): W^T bf16, fold biases, zero bin cursors. 64 blocks.
__global__ __launch_bounds__(256) void k_prep(
                       const float* __restrict__ Wxz, const float* __restrict__ bxz,
                       const float* __restrict__ bhz,
                       const float* __restrict__ Wxh, const float* __restrict__ bxh,
                       const float* __restrict__ bhh,
                       const float* __restrict__ linW, const float* __restrict__ linb,
                       float* __restrict__ bias, unsigned short* __restrict__ wt,
                       int* __restrict__ gc) {
    int idx = blockIdx.x * 256 + threadIdx.x;
    if (idx < 2 * 64 * 128) {
        int g = idx >> 13;
        int c = (idx >> 7) & 63;
        int k = idx & 127;
        const float* W = g ? Wxh : Wxz;
        float v = (k < 64) ? W[k * 64 + c] : W[4096 + (k - 64) * 64 + c];
        wt[idx] = (unsigned short)((__float_as_uint(v) + 0x8000u) >> 16);
    }
    if (idx < 64) {
        bias[idx]       = bxz[idx] + bhz[idx];
        bias[64 + idx]  = bxh[idx] + bhh[idx];
        bias[128 + idx] = linW[idx];
    }
    if (idx == 64) bias[192] = linb[0];
    if (idx < 2 * NB) gc[idx] = 0;
}

// K2: LDS-aggregated binning by dst (8B records, f32 w) and src (4B bf16 w).
__global__ __launch_bounds__(256) void k_bin(const int* __restrict__ ei,
                                             const float* __restrict__ ew,
                                             int2* __restrict__ binD,
                                             unsigned int* __restrict__ binS,
                                             int* __restrict__ gcD, int* __restrict__ gcS) {
    __shared__ int hD[NB], hS[NB], bD[NB], bS[NB];
    int t = threadIdx.x;
    for (int b = t; b < NB; b += 256) { hD[b] = 0; hS[b] = 0; }
    __syncthreads();
    int e0 = blockIdx.x * (256 * EPT);
    unsigned int sa[EPT];  // src | dlo<<16 | binD<<24
    float wv[EPT];
    int sd[EPT], ss[EPT];
#pragma unroll
    for (int i = 0; i < EPT; i++) {
        int e = e0 + i * 256 + t;
        sd[i] = -1; ss[i] = -1; sa[i] = 0; wv[i] = 0.f;
        if (e < NE) {
            int s = ei[e];
            int d = ei[NE + e];
            wv[i] = ew[e];
            int bind = d >> 8;
            sa[i] = (unsigned int)s | ((unsigned int)(d & 255) << 16)
                  | ((unsigned int)bind << 24);
            sd[i] = atomicAdd(&hD[bind], 1);
            ss[i] = atomicAdd(&hS[s >> 8], 1);
        }
    }
    __syncthreads();
    for (int b = t; b < NB; b += 256) {
        bD[b] = atomicAdd(&gcD[b], hD[b]);
        bS[b] = atomicAdd(&gcS[b], hS[b]);
    }
    __syncthreads();
#pragma unroll
    for (int i = 0; i < EPT; i++) {
        if (sd[i] < 0) continue;
        unsigned int a = sa[i];
        int bind = a >> 24;
        int src  = a & 0xffff;
        int pD = bD[bind] + sd[i];
        if (pD < BCAPD)
            binD[bind * BCAPD + pD] = make_int2((int)(a & 0xffffff),
                                                __float_as_int(wv[i]));
        int bins = src >> 8;
        int pS = bS[bins] + ss[i];
        if (pS < BCAPS)
            binS[bins * BCAPS + pS] = ((unsigned int)(src & 255) << 16)
                                    | ((__float_as_uint(wv[i]) + 0x8000u) >> 16);
    }
}

// K3 (merged): blocks [0,NB) bucket dst-records into erec (L2-window writes);
// blocks [NB,2NB) reduce src-binned weights -> deg -> dinv. Runs concurrently.
__global__ __launch_bounds__(1024) void k_split(const int2* __restrict__ binD,
                                                const unsigned int* __restrict__ binS,
                                                const int* __restrict__ gc,
                                                unsigned int* __restrict__ erec, int cap,
                                                int* __restrict__ cnt,
                                                float* __restrict__ dinv) {
    __shared__ unsigned int sh[256];
    int t = threadIdx.x;
    if (blockIdx.x < NB) {
        int bin = blockIdx.x;
        int* lcnt = (int*)sh;
        if (t < 256) lcnt[t] = 0;
        __syncthreads();
        int m = gc[bin]; if (m > BCAPD) m = BCAPD;
        const int2* bp = binD + (size_t)bin * BCAPD;
        for (int j = t; j < m; j += 1024) {
            int2 r = bp[j];
            int dlo = (r.x >> 16) & 255;
            int src = r.x & 0xffff;
            int slot = atomicAdd(&lcnt[dlo], 1);
            if (slot < cap) {
                unsigned int wr = (__float_as_uint(__int_as_float(r.y)) + 0x8000u) >> 16;
                erec[(size_t)(bin * 256 + dlo) * cap + slot] = ((unsigned int)src << 16) | wr;
            }
        }
        __syncthreads();
        if (t < 256) {
            int idx = bin * 256 + t;
            if (idx < NN) cnt[idx] = lcnt[t];
        }
    } else {
        int bin = blockIdx.x - NB;
        float* acc = (float*)sh;
        if (t < 256) acc[t] = 0.f;
        __syncthreads();
        int m = gc[NB + bin]; if (m > BCAPS) m = BCAPS;
        const unsigned int* bp = binS + (size_t)bin * BCAPS;
        for (int j = t; j < m; j += 1024) {
            unsigned int r = bp[j];
            atomicAdd(&acc[r >> 16], __uint_as_float((r & 0xffffu) << 16));
        }
        __syncthreads();
        if (t < 256) {
            int idx = bin * 256 + t;
            if (idx < NN) {
                float d = acc[t];
                dinv[idx] = (d > 0.f) ? (1.f / sqrtf(d)) : 0.f;
            }
        }
    }
}

// K4: wave per node, 4 edge-groups x 16 lanes, full 256B f32 x-row per edge;
// 2 shfl reduce + bf16 tx1 store. (round-8-proven shape, bf16 output)
__global__ __launch_bounds__(256) void k_gather(const float* __restrict__ x,
                                                const int* __restrict__ cnt,
                                                const float* __restrict__ dinv,
                                                const unsigned int* __restrict__ erec,
                                                int cap, unsigned int* __restrict__ tx1) {
    int w = (blockIdx.x * 256 + threadIdx.x) >> 6;   // node
    if (w >= NN) return;
    int lane = threadIdx.x & 63;
    int g  = lane >> 4;          // edge-group 0..3
    int c4 = (lane & 15) * 4;    // channel base
    int kn = cnt[w];
    if (kn > cap) kn = cap;
    const unsigned int* bp = erec + (size_t)w * cap;

    f4 t0 = {0.f, 0.f, 0.f, 0.f}, t1 = {0.f, 0.f, 0.f, 0.f};
    int j = 0;
    for (; j + 7 < kn; j += 8) {
        unsigned int r0 = bp[j + g];
        unsigned int r1 = bp[j + 4 + g];
        int s0 = r0 >> 16, s1 = r1 >> 16;
        float n0 = dinv[s0] * __uint_as_float((r0 & 0xffffu) << 16);
        float n1 = dinv[s1] * __uint_as_float((r1 & 0xffffu) << 16);
        const f4 x0 = *(const f4*)&x[(size_t)s0 * 64 + c4];
        const f4 x1 = *(const f4*)&x[(size_t)s1 * 64 + c4];
        t0 += n0 * x0;
        t1 += n1 * x1;
    }
    for (; j + 3 < kn; j += 4) {
        unsigned int r0 = bp[j + g];
        int s0 = r0 >> 16;
        float n0 = dinv[s0] * __uint_as_float((r0 & 0xffffu) << 16);
        t0 += n0 * (*(const f4*)&x[(size_t)s0 * 64 + c4]);
    }
    int rem = kn - j;
    if (g < rem) {
        unsigned int r = bp[j + g];
        int s0 = r >> 16;
        float n0 = dinv[s0] * __uint_as_float((r & 0xffffu) << 16);
        t0 += n0 * (*(const f4*)&x[(size_t)s0 * 64 + c4]);
    }
    f4 t = t0 + t1;
#pragma unroll
    for (int q = 0; q < 4; q++) {
        t[q] += __shfl_xor(t[q], 16);
        t[q] += __shfl_xor(t[q], 32);
    }
    if (g == 0) {
        float nd = -dinv[w];
        u32x2 o = { bpack(nd * t[0], nd * t[1]), bpack(nd * t[2], nd * t[3]) };
        *(u32x2*)&tx1[(size_t)w * 32 + (lane & 15) * 2] = o;
    }
}

// K5: MFMA node kernel, no LDS: wave = 16 nodes; x A-frags packed inline from
// f32 global, tx1 A-frags from bf16 global; C/D col=lane&15, row=(lane>>4)*4+reg.
__global__ __launch_bounds__(256) void k_node(const float* __restrict__ x,
                                              const unsigned int* __restrict__ tx1,
                                              const unsigned short* __restrict__ WT,
                                              const float* __restrict__ bias,
                                              float* __restrict__ out) {
    int lane = threadIdx.x & 63;
    int base = (blockIdx.x * 4 + (threadIdx.x >> 6)) * 16;
    if (base >= NN) return;

    int m  = lane & 15;
    int kg = lane >> 4;
    size_t node = (size_t)(base + m);

    bf16x8 afr[4];
    {
        const f4* xp0 = (const f4*)&x[node * 64 + kg * 8];        // k = kg*8 ..
        const f4* xp1 = (const f4*)&x[node * 64 + 32 + kg * 8];   // k = 32+kg*8 ..
        f4 a = xp0[0], b = xp0[1], c = xp1[0], d = xp1[1];
        u32x4 pa = { bpack(a[0], a[1]), bpack(a[2], a[3]),
                     bpack(b[0], b[1]), bpack(b[2], b[3]) };
        u32x4 pb = { bpack(c[0], c[1]), bpack(c[2], c[3]),
                     bpack(d[0], d[1]), bpack(d[2], d[3]) };
        afr[0] = *(bf16x8*)&pa;
        afr[1] = *(bf16x8*)&pb;
    }
    afr[2] = *(const bf16x8*)&tx1[node * 32 + kg * 4];
    afr[3] = *(const bf16x8*)&tx1[node * 32 + 16 + kg * 4];

    const unsigned short* Wl = WT + m * 128 + kg * 8;
    f32x4 az4[4], ah4[4];
#pragma unroll
    for (int nt = 0; nt < 4; nt++) { az4[nt] = (f32x4){0,0,0,0}; ah4[nt] = (f32x4){0,0,0,0}; }

#pragma unroll
    for (int nt = 0; nt < 4; nt++) {
#pragma unroll
        for (int kt = 0; kt < 4; kt++) {
            bf16x8 bz = *(const bf16x8*)(Wl + nt * 2048 + kt * 32);
            bf16x8 bh = *(const bf16x8*)(Wl + 8192 + nt * 2048 + kt * 32);
            az4[nt] = __builtin_amdgcn_mfma_f32_16x16x32_bf16(afr[kt], bz, az4[nt], 0, 0, 0);
            ah4[nt] = __builtin_amdgcn_mfma_f32_16x16x32_bf16(afr[kt], bh, ah4[nt], 0, 0, 0);
        }
    }

    float vout[4] = {0.f, 0.f, 0.f, 0.f};
#pragma unroll
    for (int nt = 0; nt < 4; nt++) {
        int col = nt * 16 + m;
        float bz = bias[col], bh = bias[64 + col], lw = bias[128 + col];
#pragma unroll
        for (int r = 0; r < 4; r++) {
            float az = az4[nt][r] + bz;
            float ah = ah4[nt][r] + bh;
            float ez = __expf(-az);
            float z  = __builtin_amdgcn_rcpf(1.f + ez);
            float eh = __expf(2.f * ah);
            float th = (eh - 1.f) * __builtin_amdgcn_rcpf(eh + 1.f);
            float h  = (1.f - z) * th;
            h = (h > 0.f) ? h : 0.f;
            vout[r] = fmaf(h, lw, vout[r]);
        }
    }
    float LB = bias[192];
#pragma unroll
    for (int r = 0; r < 4; r++) {
        float v = vout[r];
        v += __shfl_xor(v, 1);
        v += __shfl_xor(v, 2);
        v += __shfl_xor(v, 4);
        v += __shfl_xor(v, 8);
        if (m == 0) out[base + kg * 4 + r] = v + LB;
    }
}

extern "C" void kernel_launch(void* const* d_in, const int* in_sizes, int n_in,
                              void* d_out, int out_size, void* d_ws, size_t ws_size,
                              hipStream_t stream) {
    const float* x   = (const float*)d_in[0];
    const int*   ei  = (const int*)d_in[1];
    const float* ew  = (const float*)d_in[2];
    const float* Wxz = (const float*)d_in[3];
    const float* bxz = (const float*)d_in[4];
    const float* bhz = (const float*)d_in[6];
    const float* Wxh = (const float*)d_in[11];
    const float* bxh = (const float*)d_in[12];
    const float* bhh = (const float*)d_in[14];
    const float* lW  = (const float*)d_in[15];
    const float* lb  = (const float*)d_in[16];
    float* ws  = (float*)d_ws;
    float* out = (float*)d_out;

    long long availInts = (long long)(ws_size / 4) - (long long)OFF_EREC;
    int cap = 64;
    if (availInts < (long long)NN * 64) cap = 56;
    if (availInts < (long long)NN * 56) cap = 48;
    if (availInts < (long long)NN * 48) cap = 32;
    unsigned int* erec = (unsigned int*)(ws + OFF_EREC);

    k_prep<<<64, 256, 0, stream>>>(Wxz, bxz, bhz, Wxh, bxh, bhh, lW, lb,
                                   ws + OFF_BIAS, (unsigned short*)(ws + OFF_WT),
                                   (int*)(ws + OFF_GC));
    k_bin<<<BIN_BLOCKS, 256, 0, stream>>>(ei, ew,
                                          (int2*)(ws + OFF_BIND),
                                          (unsigned int*)(ws + OFF_BINS),
                                          (int*)(ws + OFF_GC), (int*)(ws + OFF_GC) + NB);
    k_split<<<2 * NB, 1024, 0, stream>>>((const int2*)(ws + OFF_BIND),
                                         (const unsigned int*)(ws + OFF_BINS),
                                         (const int*)(ws + OFF_GC), erec, cap,
                                         (int*)(ws + OFF_CNT), ws + OFF_DINV);
    k_gather<<<(NN * 64 + 255) / 256, 256, 0, stream>>>(
        x, (const int*)(ws + OFF_CNT), ws + OFF_DINV, erec, cap,
        (unsigned int*)(ws + OFF_TX1));
    k_node<<<(NN + 63) / 64, 256, 0, stream>>>(
        x, (const unsigned int*)(ws + OFF_TX1),
        (const unsigned short*)(ws + OFF_WT), ws + OFF_BIAS, out);
}